// Round 1
// baseline (6752.783 us; speedup 1.0000x reference)
//
#include <hip/hip_runtime.h>

// Problem: B=512, T-1=128, D=128, H=512, 4H=2048.
// Key identity: softmax(proj_x + shift[:,None]) == softmax(proj_x)  (shift is
// per-row constant) => attention weights are timestep-invariant and do not
// depend on h/c. Only the LSTM recurrence is sequential.

typedef __attribute__((ext_vector_type(8))) short short8;
typedef __attribute__((ext_vector_type(4))) float floatx4;
typedef __attribute__((ext_vector_type(4))) unsigned int uintx4;

#define NB 512      // batch
#define NT 128      // timesteps
#define ND 128      // input dim
#define NH 512      // hidden

static __device__ __forceinline__ unsigned short f2bf(float f) {
  unsigned int u = __float_as_uint(f);
  u += 0x7fffu + ((u >> 16) & 1u);   // RNE
  return (unsigned short)(u >> 16);
}

// ---------------------------------------------------------------------------
// Kernel A: attn[b,d] = softmax_d( sum_t in[b,t,d]*wx[t] ); out0 = attn*in
// ---------------------------------------------------------------------------
__global__ __launch_bounds__(128) void attn_kernel(
    const float* __restrict__ in, const float* __restrict__ attn_W,
    float* __restrict__ out0, float* __restrict__ attn_ws) {
  const int b = blockIdx.x;
  const int d = threadIdx.x;          // 0..127
  __shared__ float wx[NT];
  __shared__ float red[4];
  wx[d] = attn_W[2 * NH + d];         // wx[t] = attn_W[0][1024 + t]
  __syncthreads();
  const float* ib = in + (size_t)b * (NT * ND);
  float p = 0.f;
#pragma unroll 8
  for (int t = 0; t < NT; ++t) p = fmaf(ib[t * ND + d], wx[t], p);
  // block softmax over 128 lanes (2 waves)
  float m = p;
#pragma unroll
  for (int off = 32; off >= 1; off >>= 1) m = fmaxf(m, __shfl_xor(m, off));
  const int wv = d >> 6;
  if ((d & 63) == 0) red[wv] = m;
  __syncthreads();
  const float M = fmaxf(red[0], red[1]);
  const float e = expf(p - M);
  float s = e;
#pragma unroll
  for (int off = 32; off >= 1; off >>= 1) s += __shfl_xor(s, off);
  if ((d & 63) == 0) red[2 + wv] = s;
  __syncthreads();
  const float a = e / (red[2] + red[3]);
  attn_ws[b * ND + d] = a;
#pragma unroll 4
  for (int t = 0; t < NT; ++t)
    out0[(size_t)b * (NT * ND) + t * ND + d] = a * ib[t * ND + d];
}

// ---------------------------------------------------------------------------
// Kernel C: persistent fused LSTM recurrence.
// 256 blocks x 512 threads, 128KB LDS => exactly 1 block/CU => all blocks
// co-resident => group spin-sync is deadlock-free.
// Block (gid = bid&7, sid = bid>>3): batch rows [gid*64, +64), hidden cols
// [sid*16, +16) (x 4 gates = 64 GEMM columns). Weight slices live in LDS
// (bf16, XOR-swizzled) for the whole kernel. c-state lives in registers.
// ---------------------------------------------------------------------------
#define WI_OFF 0        // W_ih slice  [64][128] bf16  (16 KB)
#define WH_OFF 16384    // W_hh slice  [64][512] bf16  (64 KB)
#define HH_OFF 81920    // h half-tile [64][256] bf16  (32 KB)
#define WT_OFF 114688   // wi tile [64][128] bf16  OR gates [4][64][16] f32 (16 KB)

__global__ __launch_bounds__(512) void rec_kernel(
    const float* __restrict__ in, const float* __restrict__ W_ih,
    const float* __restrict__ W_hh, const float* __restrict__ b_ih,
    const float* __restrict__ b_hh, const float* __restrict__ attn_ws,
    unsigned short* __restrict__ hbuf, unsigned int* __restrict__ cnt,
    float* __restrict__ out1) {
  __shared__ __align__(16) unsigned char LDS[131072];
  const int tid = threadIdx.x;
  const int bid = blockIdx.x;
  const int gid = bid & 7;          // batch group (XCD-local under round-robin)
  const int sid = bid >> 3;         // n-slice
  const int b0 = gid * 64;
  const int n0 = sid * 16;
  const int lane = tid & 63;
  const int wid = tid >> 6;
  const int rh = wid & 1;           // row half (32 rows)
  const int gate = wid >> 1;        // 0..3 -> i,f,g,o

  // --- W_ih slice -> LDS (bf16, swizzled: byte ^= ((row&7)<<4)) ---
#pragma unroll 4
  for (int it = 0; it < 16; ++it) {
    const int jj = it * 4 + (tid >> 7);           // 0..63
    const int k = tid & 127;
    const int j = (jj >> 4) * NH + n0 + (jj & 15);   // gate*512 + n0 + nn
    *(unsigned short*)&LDS[WI_OFF + jj * 256 + ((2 * k) ^ ((jj & 7) << 4))] =
        f2bf(W_ih[j * ND + k]);
  }
  // --- W_hh slice -> LDS ---
#pragma unroll 8
  for (int jj = 0; jj < 64; ++jj) {
    const int k = tid;                              // 0..511
    const int j = (jj >> 4) * NH + n0 + (jj & 15);
    *(unsigned short*)&LDS[WH_OFF + jj * 1024 + ((2 * k) ^ ((jj & 7) << 4))] =
        f2bf(W_hh[j * NH + k]);
  }
  // --- attention weights -> registers (t-invariant) ---
  const int rA = tid >> 3;          // staging row 0..63
  const int pA = tid & 7;           // 16-element chunk 0..7
  float areg[16];
  {
    const float* ap = attn_ws + (b0 + rA) * ND + pA * 16;
#pragma unroll
    for (int i = 0; i < 16; ++i) areg[i] = ap[i];
  }
  // --- biases for this thread's output column (t-invariant) ---
  const int colC = tid & 15;
  const int jC = n0 + colC;
  const float bi_i = b_ih[jC] + b_hh[jC];
  const float bi_f = b_ih[NH + jC] + b_hh[NH + jC];
  const float bi_g = b_ih[2 * NH + jC] + b_hh[2 * NH + jC];
  const float bi_o = b_ih[3 * NH + jC] + b_hh[3 * NH + jC];
  float creg0 = 0.f, creg1 = 0.f;

  const int jjB = gate * 16 + (lane & 15);
  const int kg = lane >> 4;          // 0..3
  const int rowa0 = rh * 32 + (lane & 15);
  const int rowa1 = rowa0 + 16;
  unsigned int* cptr = &cnt[gid * 32];   // 128B-strided counters

  __syncthreads();

  for (int t = 0; t < NT; ++t) {
    // ---- stage wi tile: wi = attn * x_t, bf16 swizzled into WT ----
    {
      const float* xs = in + ((size_t)(b0 + rA) * NT + t) * ND + pA * 16;
      floatx4 x0 = *(const floatx4*)(xs);
      floatx4 x1 = *(const floatx4*)(xs + 4);
      floatx4 x2 = *(const floatx4*)(xs + 8);
      floatx4 x3 = *(const floatx4*)(xs + 12);
      float xv[16];
#pragma unroll
      for (int i = 0; i < 4; ++i) { xv[i] = x0[i]; xv[4+i] = x1[i]; xv[8+i] = x2[i]; xv[12+i] = x3[i]; }
      unsigned int w[8];
#pragma unroll
      for (int i = 0; i < 8; ++i)
        w[i] = (unsigned int)f2bf(xv[2*i] * areg[2*i]) |
               ((unsigned int)f2bf(xv[2*i+1] * areg[2*i+1]) << 16);
      const int base = WT_OFF + rA * 256;
      const int sw = (rA & 7) << 4;
      uintx4 lo = {w[0], w[1], w[2], w[3]};
      uintx4 hi = {w[4], w[5], w[6], w[7]};
      *(uintx4*)&LDS[base + ((pA * 32) ^ sw)] = lo;
      *(uintx4*)&LDS[base + ((pA * 32 + 16) ^ sw)] = hi;
    }
    // ---- stage h first half (k in [0,256)) ----
    if (t > 0) {
      const unsigned short* hsrc = hbuf + (size_t)(t & 1) * (NB * NH);
#pragma unroll
      for (int pass = 0; pass < 4; ++pass) {
        const int idx = pass * 512 + tid;
        const int r2 = idx >> 5;
        const int seg = idx & 31;
        uintx4 v = *(const uintx4*)(hsrc + (b0 + r2) * NH + seg * 8);
        *(uintx4*)&LDS[HH_OFF + r2 * 512 + ((seg * 16) ^ ((r2 & 7) << 4))] = v;
      }
    }
    __syncthreads();

    floatx4 acc0 = {0.f, 0.f, 0.f, 0.f};
    floatx4 acc1 = {0.f, 0.f, 0.f, 0.f};
    // ---- wi contribution: K = 128 ----
#pragma unroll
    for (int ks = 0; ks < 4; ++ks) {
      const int k2 = (ks * 32 + kg * 8) * 2;
      short8 bf = *(const short8*)&LDS[WI_OFF + jjB * 256 + (k2 ^ ((jjB & 7) << 4))];
      short8 a0 = *(const short8*)&LDS[WT_OFF + rowa0 * 256 + (k2 ^ ((rowa0 & 7) << 4))];
      short8 a1 = *(const short8*)&LDS[WT_OFF + rowa1 * 256 + (k2 ^ ((rowa1 & 7) << 4))];
      acc0 = __builtin_amdgcn_mfma_f32_16x16x32_bf16(a0, bf, acc0, 0, 0, 0);
      acc1 = __builtin_amdgcn_mfma_f32_16x16x32_bf16(a1, bf, acc1, 0, 0, 0);
    }
    if (t > 0) {
      // ---- h contribution, first half ----
#pragma unroll
      for (int ks = 0; ks < 8; ++ks) {
        const int k2 = (ks * 32 + kg * 8) * 2;
        short8 bf = *(const short8*)&LDS[WH_OFF + jjB * 1024 + (k2 ^ ((jjB & 7) << 4))];
        short8 a0 = *(const short8*)&LDS[HH_OFF + rowa0 * 512 + (k2 ^ ((rowa0 & 7) << 4))];
        short8 a1 = *(const short8*)&LDS[HH_OFF + rowa1 * 512 + (k2 ^ ((rowa1 & 7) << 4))];
        acc0 = __builtin_amdgcn_mfma_f32_16x16x32_bf16(a0, bf, acc0, 0, 0, 0);
        acc1 = __builtin_amdgcn_mfma_f32_16x16x32_bf16(a1, bf, acc1, 0, 0, 0);
      }
      __syncthreads();
      // ---- stage h second half (k in [256,512)) ----
      {
        const unsigned short* hsrc = hbuf + (size_t)(t & 1) * (NB * NH) + 256;
#pragma unroll
        for (int pass = 0; pass < 4; ++pass) {
          const int idx = pass * 512 + tid;
          const int r2 = idx >> 5;
          const int seg = idx & 31;
          uintx4 v = *(const uintx4*)(hsrc + (b0 + r2) * NH + seg * 8);
          *(uintx4*)&LDS[HH_OFF + r2 * 512 + ((seg * 16) ^ ((r2 & 7) << 4))] = v;
        }
      }
      __syncthreads();
      // ---- h contribution, second half ----
#pragma unroll
      for (int ks = 0; ks < 8; ++ks) {
        const int kl2 = (ks * 32 + kg * 8) * 2;    // local byte-k in HH
        const int kgl2 = kl2 + 512;                // global byte-k in WH
        short8 bf = *(const short8*)&LDS[WH_OFF + jjB * 1024 + (kgl2 ^ ((jjB & 7) << 4))];
        short8 a0 = *(const short8*)&LDS[HH_OFF + rowa0 * 512 + (kl2 ^ ((rowa0 & 7) << 4))];
        short8 a1 = *(const short8*)&LDS[HH_OFF + rowa1 * 512 + (kl2 ^ ((rowa1 & 7) << 4))];
        acc0 = __builtin_amdgcn_mfma_f32_16x16x32_bf16(a0, bf, acc0, 0, 0, 0);
        acc1 = __builtin_amdgcn_mfma_f32_16x16x32_bf16(a1, bf, acc1, 0, 0, 0);
      }
    } else {
      __syncthreads();   // protect WT (wi) reads before gate overlay at t==0
    }
    // ---- write gates fp32 into WT overlay: [gate][row 0..63][col 0..15] ----
    {
      const int colG = lane & 15;
      const int gbase = WT_OFF + gate * 4096;
#pragma unroll
      for (int r = 0; r < 4; ++r) {
        const int row0 = rh * 32 + kg * 4 + r;     // C layout: row=(lane>>4)*4+reg
        *(float*)&LDS[gbase + (row0 * 16 + colG) * 4] = acc0[r];
        *(float*)&LDS[gbase + ((row0 + 16) * 16 + colG) * 4] = acc1[r];
      }
    }
    __syncthreads();
    // ---- LSTM pointwise: 2 cells per thread ----
#pragma unroll
    for (int cc = 0; cc < 2; ++cc) {
      const int cell = cc * 512 + tid;
      const int row = cell >> 4;
      const float gi = *(const float*)&LDS[WT_OFF + 0 * 4096 + (row * 16 + colC) * 4] + bi_i;
      const float gf = *(const float*)&LDS[WT_OFF + 1 * 4096 + (row * 16 + colC) * 4] + bi_f;
      const float gg = *(const float*)&LDS[WT_OFF + 2 * 4096 + (row * 16 + colC) * 4] + bi_g;
      const float go = *(const float*)&LDS[WT_OFF + 3 * 4096 + (row * 16 + colC) * 4] + bi_o;
      const float c_old = cc ? creg1 : creg0;
      const float si = 1.f / (1.f + expf(-gi));
      const float sf = 1.f / (1.f + expf(-gf));
      const float so = 1.f / (1.f + expf(-go));
      const float cn = sf * c_old + si * tanhf(gg);
      const float hn = so * tanhf(cn);
      if (cc) creg1 = cn; else creg0 = cn;
      const int b = b0 + row;
      out1[((size_t)b * NT + t) * NH + jC] = hn;
      hbuf[(size_t)((t + 1) & 1) * (NB * NH) + b * NH + jC] = f2bf(hn);
    }
    // ---- group arrival sync (32 blocks/group, monotonic counter) ----
    __threadfence();
    __syncthreads();
    if (tid == 0) {
      __hip_atomic_fetch_add(cptr, 1u, __ATOMIC_RELEASE, __HIP_MEMORY_SCOPE_AGENT);
      const unsigned int target = 32u * (unsigned int)(t + 1);
      while (__hip_atomic_load(cptr, __ATOMIC_RELAXED, __HIP_MEMORY_SCOPE_AGENT) < target) {
        __builtin_amdgcn_s_sleep(1);
      }
      __threadfence();   // acquire: invalidate L1/L2 before reading new h
    }
    __syncthreads();
  }
}

// ---------------------------------------------------------------------------
extern "C" void kernel_launch(void* const* d_in, const int* in_sizes, int n_in,
                              void* d_out, int out_size, void* d_ws, size_t ws_size,
                              hipStream_t stream) {
  (void)in_sizes; (void)n_in; (void)out_size; (void)ws_size;
  const float* in     = (const float*)d_in[0];
  const float* W_ih   = (const float*)d_in[1];
  const float* W_hh   = (const float*)d_in[2];
  const float* b_ih   = (const float*)d_in[3];
  const float* b_hh   = (const float*)d_in[4];
  const float* attn_W = (const float*)d_in[5];
  // d_in[6] (attn_b) cancels in the softmax -> unused.

  float* out0 = (float*)d_out;                         // (512,128,128)
  float* out1 = out0 + (size_t)NB * NT * ND;           // (512,128,512)

  // workspace layout
  float* attn_ws = (float*)d_ws;                                   // 256 KB
  unsigned short* hbuf = (unsigned short*)((char*)d_ws + 262144);  // 1 MB (2 x 512 x 512 bf16)
  unsigned int* cnt = (unsigned int*)((char*)d_ws + 262144 + 1048576); // 1 KB

  hipMemsetAsync(cnt, 0, 8 * 128, stream);
  attn_kernel<<<NB, 128, 0, stream>>>(in, attn_W, out0, attn_ws);
  rec_kernel<<<256, 512, 0, stream>>>(in, W_ih, W_hh, b_ih, b_hh, attn_ws,
                                      hbuf, cnt, out1);
}

// Round 2
// 798.822 us; speedup vs baseline: 8.4534x; 8.4534x over previous
//
#include <hip/hip_runtime.h>

// Problem: B=512, T-1=128, D=128, H=512, 4H=2048.
// Key identity: softmax(proj_x + shift[:,None]) == softmax(proj_x)  (shift is
// per-row constant) => attention weights are timestep-invariant and do not
// depend on h/c. Only the LSTM recurrence is sequential.
//
// R2: cross-block h hand-off + counters go through MALL via relaxed
// agent-scope atomics (sc0/sc1 loads/stores, no buffer_wbl2/buffer_inv
// fences). out1 stores nontemporal. This removes the per-step L2
// writeback/invalidate that made R1 6.8 ms (97% idle).

typedef __attribute__((ext_vector_type(8))) short short8;
typedef __attribute__((ext_vector_type(4))) float floatx4;
typedef __attribute__((ext_vector_type(4))) unsigned int uintx4;

#define NB 512      // batch
#define NT 128      // timesteps
#define ND 128      // input dim
#define NH 512      // hidden

static __device__ __forceinline__ unsigned short f2bf(float f) {
  unsigned int u = __float_as_uint(f);
  u += 0x7fffu + ((u >> 16) & 1u);   // RNE
  return (unsigned short)(u >> 16);
}

// ---------------------------------------------------------------------------
// Kernel A: attn[b,d] = softmax_d( sum_t in[b,t,d]*wx[t] ); out0 = attn*in
// ---------------------------------------------------------------------------
__global__ __launch_bounds__(128) void attn_kernel(
    const float* __restrict__ in, const float* __restrict__ attn_W,
    float* __restrict__ out0, float* __restrict__ attn_ws) {
  const int b = blockIdx.x;
  const int d = threadIdx.x;          // 0..127
  __shared__ float wx[NT];
  __shared__ float red[4];
  wx[d] = attn_W[2 * NH + d];         // wx[t] = attn_W[0][1024 + t]
  __syncthreads();
  const float* ib = in + (size_t)b * (NT * ND);
  float p = 0.f;
#pragma unroll 8
  for (int t = 0; t < NT; ++t) p = fmaf(ib[t * ND + d], wx[t], p);
  // block softmax over 128 lanes (2 waves)
  float m = p;
#pragma unroll
  for (int off = 32; off >= 1; off >>= 1) m = fmaxf(m, __shfl_xor(m, off));
  const int wv = d >> 6;
  if ((d & 63) == 0) red[wv] = m;
  __syncthreads();
  const float M = fmaxf(red[0], red[1]);
  const float e = expf(p - M);
  float s = e;
#pragma unroll
  for (int off = 32; off >= 1; off >>= 1) s += __shfl_xor(s, off);
  if ((d & 63) == 0) red[2 + wv] = s;
  __syncthreads();
  const float a = e / (red[2] + red[3]);
  attn_ws[b * ND + d] = a;
#pragma unroll 4
  for (int t = 0; t < NT; ++t)
    out0[(size_t)b * (NT * ND) + t * ND + d] = a * ib[t * ND + d];
}

// ---------------------------------------------------------------------------
// Kernel C: persistent fused LSTM recurrence.
// 256 blocks x 512 threads, 128KB LDS => exactly 1 block/CU => all blocks
// co-resident => group spin-sync is deadlock-free.
// Block (gid = bid&7, sid = bid>>3): batch rows [gid*64, +64), hidden cols
// [sid*16, +16) (x 4 gates = 64 GEMM columns). Weight slices live in LDS
// (bf16, XOR-swizzled) for the whole kernel. c-state lives in registers.
// ---------------------------------------------------------------------------
#define WI_OFF 0        // W_ih slice  [64][128] bf16  (16 KB)
#define WH_OFF 16384    // W_hh slice  [64][512] bf16  (64 KB)
#define HH_OFF 81920    // h half-tile [64][256] bf16  (32 KB)
#define WT_OFF 114688   // wi tile [64][128] bf16  OR gates [4][64][16] f32 (16 KB)

__global__ __launch_bounds__(512) void rec_kernel(
    const float* __restrict__ in, const float* __restrict__ W_ih,
    const float* __restrict__ W_hh, const float* __restrict__ b_ih,
    const float* __restrict__ b_hh, const float* __restrict__ attn_ws,
    unsigned short* __restrict__ hbuf, unsigned int* __restrict__ cnt,
    float* __restrict__ out1) {
  __shared__ __align__(16) unsigned char LDS[131072];
  const int tid = threadIdx.x;
  const int bid = blockIdx.x;
  const int gid = bid & 7;          // batch group
  const int sid = bid >> 3;         // n-slice
  const int b0 = gid * 64;
  const int n0 = sid * 16;
  const int lane = tid & 63;
  const int wid = tid >> 6;
  const int rh = wid & 1;           // row half (32 rows)
  const int gate = wid >> 1;        // 0..3 -> i,f,g,o

  // --- W_ih slice -> LDS (bf16, swizzled: byte ^= ((row&7)<<4)) ---
#pragma unroll 4
  for (int it = 0; it < 16; ++it) {
    const int jj = it * 4 + (tid >> 7);           // 0..63
    const int k = tid & 127;
    const int j = (jj >> 4) * NH + n0 + (jj & 15);   // gate*512 + n0 + nn
    *(unsigned short*)&LDS[WI_OFF + jj * 256 + ((2 * k) ^ ((jj & 7) << 4))] =
        f2bf(W_ih[j * ND + k]);
  }
  // --- W_hh slice -> LDS ---
#pragma unroll 8
  for (int jj = 0; jj < 64; ++jj) {
    const int k = tid;                              // 0..511
    const int j = (jj >> 4) * NH + n0 + (jj & 15);
    *(unsigned short*)&LDS[WH_OFF + jj * 1024 + ((2 * k) ^ ((jj & 7) << 4))] =
        f2bf(W_hh[j * NH + k]);
  }
  // --- attention weights -> registers (t-invariant) ---
  const int rA = tid >> 3;          // staging row 0..63
  const int pA = tid & 7;           // 16-element chunk 0..7
  float areg[16];
  {
    const float* ap = attn_ws + (b0 + rA) * ND + pA * 16;
#pragma unroll
    for (int i = 0; i < 16; ++i) areg[i] = ap[i];
  }
  // --- biases for this thread's output column (t-invariant) ---
  const int colC = tid & 15;
  const int jC = n0 + colC;
  const float bi_i = b_ih[jC] + b_hh[jC];
  const float bi_f = b_ih[NH + jC] + b_hh[NH + jC];
  const float bi_g = b_ih[2 * NH + jC] + b_hh[2 * NH + jC];
  const float bi_o = b_ih[3 * NH + jC] + b_hh[3 * NH + jC];
  float creg0 = 0.f, creg1 = 0.f;

  const int jjB = gate * 16 + (lane & 15);
  const int kg = lane >> 4;          // 0..3
  const int rowa0 = rh * 32 + (lane & 15);
  const int rowa1 = rowa0 + 16;
  unsigned int* cptr = &cnt[gid * 32];   // 128B-strided counters

  // staging geometry for h tiles
  const int rS = tid >> 3;           // not used for h; h uses idx math below

  __syncthreads();

  for (int t = 0; t < NT; ++t) {
    // ---- stage wi tile: wi = attn * x_t, bf16 swizzled into WT ----
    {
      const float* xs = in + ((size_t)(b0 + rA) * NT + t) * ND + pA * 16;
      floatx4 x0 = *(const floatx4*)(xs);
      floatx4 x1 = *(const floatx4*)(xs + 4);
      floatx4 x2 = *(const floatx4*)(xs + 8);
      floatx4 x3 = *(const floatx4*)(xs + 12);
      float xv[16];
#pragma unroll
      for (int i = 0; i < 4; ++i) { xv[i] = x0[i]; xv[4+i] = x1[i]; xv[8+i] = x2[i]; xv[12+i] = x3[i]; }
      unsigned int w[8];
#pragma unroll
      for (int i = 0; i < 8; ++i)
        w[i] = (unsigned int)f2bf(xv[2*i] * areg[2*i]) |
               ((unsigned int)f2bf(xv[2*i+1] * areg[2*i+1]) << 16);
      const int base = WT_OFF + rA * 256;
      const int sw = (rA & 7) << 4;
      uintx4 lo = {w[0], w[1], w[2], w[3]};
      uintx4 hi = {w[4], w[5], w[6], w[7]};
      *(uintx4*)&LDS[base + ((pA * 32) ^ sw)] = lo;
      *(uintx4*)&LDS[base + ((pA * 32 + 16) ^ sw)] = hi;
    }
    // ---- stage h first half (k in [0,256)) via MALL-coherent loads ----
    if (t > 0) {
      const unsigned short* hsrc = hbuf + (size_t)(t & 1) * (NB * NH);
      unsigned long long q[8];
#pragma unroll
      for (int pass = 0; pass < 4; ++pass) {
        const int idx = pass * 512 + tid;
        const int r2 = idx >> 5;
        const int seg = idx & 31;
        const unsigned long long* src =
            (const unsigned long long*)(hsrc + (b0 + r2) * NH + seg * 8);
        q[2 * pass]     = __hip_atomic_load(src,     __ATOMIC_RELAXED, __HIP_MEMORY_SCOPE_AGENT);
        q[2 * pass + 1] = __hip_atomic_load(src + 1, __ATOMIC_RELAXED, __HIP_MEMORY_SCOPE_AGENT);
      }
#pragma unroll
      for (int pass = 0; pass < 4; ++pass) {
        const int idx = pass * 512 + tid;
        const int r2 = idx >> 5;
        const int seg = idx & 31;
        uintx4 v;
        v[0] = (unsigned int)q[2 * pass];
        v[1] = (unsigned int)(q[2 * pass] >> 32);
        v[2] = (unsigned int)q[2 * pass + 1];
        v[3] = (unsigned int)(q[2 * pass + 1] >> 32);
        *(uintx4*)&LDS[HH_OFF + r2 * 512 + ((seg * 16) ^ ((r2 & 7) << 4))] = v;
      }
    }
    __syncthreads();

    floatx4 acc0 = {0.f, 0.f, 0.f, 0.f};
    floatx4 acc1 = {0.f, 0.f, 0.f, 0.f};
    // ---- wi contribution: K = 128 ----
#pragma unroll
    for (int ks = 0; ks < 4; ++ks) {
      const int k2 = (ks * 32 + kg * 8) * 2;
      short8 bf = *(const short8*)&LDS[WI_OFF + jjB * 256 + (k2 ^ ((jjB & 7) << 4))];
      short8 a0 = *(const short8*)&LDS[WT_OFF + rowa0 * 256 + (k2 ^ ((rowa0 & 7) << 4))];
      short8 a1 = *(const short8*)&LDS[WT_OFF + rowa1 * 256 + (k2 ^ ((rowa1 & 7) << 4))];
      acc0 = __builtin_amdgcn_mfma_f32_16x16x32_bf16(a0, bf, acc0, 0, 0, 0);
      acc1 = __builtin_amdgcn_mfma_f32_16x16x32_bf16(a1, bf, acc1, 0, 0, 0);
    }
    if (t > 0) {
      // ---- h contribution, first half ----
#pragma unroll
      for (int ks = 0; ks < 8; ++ks) {
        const int k2 = (ks * 32 + kg * 8) * 2;
        short8 bf = *(const short8*)&LDS[WH_OFF + jjB * 1024 + (k2 ^ ((jjB & 7) << 4))];
        short8 a0 = *(const short8*)&LDS[HH_OFF + rowa0 * 512 + (k2 ^ ((rowa0 & 7) << 4))];
        short8 a1 = *(const short8*)&LDS[HH_OFF + rowa1 * 512 + (k2 ^ ((rowa1 & 7) << 4))];
        acc0 = __builtin_amdgcn_mfma_f32_16x16x32_bf16(a0, bf, acc0, 0, 0, 0);
        acc1 = __builtin_amdgcn_mfma_f32_16x16x32_bf16(a1, bf, acc1, 0, 0, 0);
      }
      __syncthreads();
      // ---- stage h second half (k in [256,512)) ----
      {
        const unsigned short* hsrc = hbuf + (size_t)(t & 1) * (NB * NH) + 256;
        unsigned long long q[8];
#pragma unroll
        for (int pass = 0; pass < 4; ++pass) {
          const int idx = pass * 512 + tid;
          const int r2 = idx >> 5;
          const int seg = idx & 31;
          const unsigned long long* src =
              (const unsigned long long*)(hsrc + (b0 + r2) * NH + seg * 8);
          q[2 * pass]     = __hip_atomic_load(src,     __ATOMIC_RELAXED, __HIP_MEMORY_SCOPE_AGENT);
          q[2 * pass + 1] = __hip_atomic_load(src + 1, __ATOMIC_RELAXED, __HIP_MEMORY_SCOPE_AGENT);
        }
#pragma unroll
        for (int pass = 0; pass < 4; ++pass) {
          const int idx = pass * 512 + tid;
          const int r2 = idx >> 5;
          const int seg = idx & 31;
          uintx4 v;
          v[0] = (unsigned int)q[2 * pass];
          v[1] = (unsigned int)(q[2 * pass] >> 32);
          v[2] = (unsigned int)q[2 * pass + 1];
          v[3] = (unsigned int)(q[2 * pass + 1] >> 32);
          *(uintx4*)&LDS[HH_OFF + r2 * 512 + ((seg * 16) ^ ((r2 & 7) << 4))] = v;
        }
      }
      __syncthreads();
      // ---- h contribution, second half ----
#pragma unroll
      for (int ks = 0; ks < 8; ++ks) {
        const int kl2 = (ks * 32 + kg * 8) * 2;    // local byte-k in HH
        const int kgl2 = kl2 + 512;                // global byte-k in WH
        short8 bf = *(const short8*)&LDS[WH_OFF + jjB * 1024 + (kgl2 ^ ((jjB & 7) << 4))];
        short8 a0 = *(const short8*)&LDS[HH_OFF + rowa0 * 512 + (kl2 ^ ((rowa0 & 7) << 4))];
        short8 a1 = *(const short8*)&LDS[HH_OFF + rowa1 * 512 + (kl2 ^ ((rowa1 & 7) << 4))];
        acc0 = __builtin_amdgcn_mfma_f32_16x16x32_bf16(a0, bf, acc0, 0, 0, 0);
        acc1 = __builtin_amdgcn_mfma_f32_16x16x32_bf16(a1, bf, acc1, 0, 0, 0);
      }
    } else {
      __syncthreads();   // protect WT (wi) reads before gate overlay at t==0
    }
    // ---- write gates fp32 into WT overlay: [gate][row 0..63][col 0..15] ----
    {
      const int colG = lane & 15;
      const int gbase = WT_OFF + gate * 4096;
#pragma unroll
      for (int r = 0; r < 4; ++r) {
        const int row0 = rh * 32 + kg * 4 + r;     // C layout: row=(lane>>4)*4+reg
        *(float*)&LDS[gbase + (row0 * 16 + colG) * 4] = acc0[r];
        *(float*)&LDS[gbase + ((row0 + 16) * 16 + colG) * 4] = acc1[r];
      }
    }
    __syncthreads();
    // ---- LSTM pointwise: 2 cells per thread ----
    unsigned int hb0, hb1;
#pragma unroll
    for (int cc = 0; cc < 2; ++cc) {
      const int cell = cc * 512 + tid;
      const int row = cell >> 4;
      const float gi = *(const float*)&LDS[WT_OFF + 0 * 4096 + (row * 16 + colC) * 4] + bi_i;
      const float gf = *(const float*)&LDS[WT_OFF + 1 * 4096 + (row * 16 + colC) * 4] + bi_f;
      const float gg = *(const float*)&LDS[WT_OFF + 2 * 4096 + (row * 16 + colC) * 4] + bi_g;
      const float go = *(const float*)&LDS[WT_OFF + 3 * 4096 + (row * 16 + colC) * 4] + bi_o;
      const float c_old = cc ? creg1 : creg0;
      const float si = 1.f / (1.f + expf(-gi));
      const float sf = 1.f / (1.f + expf(-gf));
      const float so = 1.f / (1.f + expf(-go));
      const float cn = sf * c_old + si * tanhf(gg);
      const float hn = so * tanhf(cn);
      if (cc) creg1 = cn; else creg0 = cn;
      const int b = b0 + row;
      __builtin_nontemporal_store(hn, &out1[((size_t)b * NT + t) * NH + jC]);
      const unsigned int m = (unsigned int)f2bf(hn);
      if (cc) hb1 = m; else hb0 = m;
    }
    // ---- h hand-off: packed 4B MALL-coherent stores (lane-pair pack) ----
    {
      const unsigned int o0 = __shfl_xor(hb0, 1);
      const unsigned int o1 = __shfl_xor(hb1, 1);
      if ((tid & 1) == 0) {
        unsigned short* hdst = hbuf + (size_t)((t + 1) & 1) * (NB * NH);
        const int row0 = tid >> 4;
        const int row1 = 32 + (tid >> 4);
        unsigned int* p0 = (unsigned int*)(hdst + (size_t)(b0 + row0) * NH + jC);
        unsigned int* p1 = (unsigned int*)(hdst + (size_t)(b0 + row1) * NH + jC);
        __hip_atomic_store(p0, hb0 | (o0 << 16), __ATOMIC_RELAXED, __HIP_MEMORY_SCOPE_AGENT);
        __hip_atomic_store(p1, hb1 | (o1 << 16), __ATOMIC_RELAXED, __HIP_MEMORY_SCOPE_AGENT);
      }
    }
    // ---- group arrival sync: HW-ordered release (vmcnt drain, no L2 flush) --
    asm volatile("s_waitcnt vmcnt(0)" ::: "memory");   // h stores ACK'd at MALL
    __syncthreads();                                   // all waves drained
    if (tid == 0) {
      __hip_atomic_fetch_add(cptr, 1u, __ATOMIC_RELAXED, __HIP_MEMORY_SCOPE_AGENT);
      const unsigned int target = 32u * (unsigned int)(t + 1);
      while (__hip_atomic_load(cptr, __ATOMIC_RELAXED, __HIP_MEMORY_SCOPE_AGENT) < target) {
        __builtin_amdgcn_s_sleep(1);
      }
    }
    __syncthreads();
    __builtin_amdgcn_sched_barrier(0);   // keep next-step h loads below barrier
  }
  (void)rS;
}

// ---------------------------------------------------------------------------
extern "C" void kernel_launch(void* const* d_in, const int* in_sizes, int n_in,
                              void* d_out, int out_size, void* d_ws, size_t ws_size,
                              hipStream_t stream) {
  (void)in_sizes; (void)n_in; (void)out_size; (void)ws_size;
  const float* in     = (const float*)d_in[0];
  const float* W_ih   = (const float*)d_in[1];
  const float* W_hh   = (const float*)d_in[2];
  const float* b_ih   = (const float*)d_in[3];
  const float* b_hh   = (const float*)d_in[4];
  const float* attn_W = (const float*)d_in[5];
  // d_in[6] (attn_b) cancels in the softmax -> unused.

  float* out0 = (float*)d_out;                         // (512,128,128)
  float* out1 = out0 + (size_t)NB * NT * ND;           // (512,128,512)

  // workspace layout
  float* attn_ws = (float*)d_ws;                                   // 256 KB
  unsigned short* hbuf = (unsigned short*)((char*)d_ws + 262144);  // 1 MB (2 x 512 x 512 bf16)
  unsigned int* cnt = (unsigned int*)((char*)d_ws + 262144 + 1048576); // 1 KB

  hipMemsetAsync(cnt, 0, 8 * 128, stream);
  attn_kernel<<<NB, 128, 0, stream>>>(in, attn_W, out0, attn_ws);
  rec_kernel<<<256, 512, 0, stream>>>(in, W_ih, W_hh, b_ih, b_hh, attn_ws,
                                      hbuf, cnt, out1);
}

// Round 3
// 542.601 us; speedup vs baseline: 12.4452x; 1.4722x over previous
//
#include <hip/hip_runtime.h>

// Problem: B=512, T-1=128, D=128, H=512, 4H=2048.
// Key identity: softmax(proj_x + shift[:,None]) == softmax(proj_x) => attention
// is timestep-invariant; only the LSTM recurrence is sequential.
//
// R3: weights live in REGISTERS (zero B-side LDS traffic); 2x2x2 wave grid
// (row x col x K-half) halves A-side LDS traffic; full 64KB h-tile staged in
// one phase; flag-array group sync; h-load MALL latency overlapped with
// wi-MFMAs; fast transcendentals.

typedef __attribute__((ext_vector_type(8))) short short8;
typedef __attribute__((ext_vector_type(4))) float floatx4;
typedef __attribute__((ext_vector_type(4))) unsigned int uintx4;

#define NB 512
#define NT 128
#define ND 128
#define NH 512

// LDS layout (115712 B total)
#define HH_OFF 0          // h tile [64][512] bf16, swizzled (64 KB)
#define WT_OFF 65536      // wi tile [64][128] bf16, swizzled (16 KB)
#define GT_OFF 81920      // gates [2 kh][64][66] f32 (33792 B)
#define GT_KH  16896      // 64*66*4
#define LDS_BYTES 115712

static __device__ __forceinline__ unsigned short f2bf(float f) {
  unsigned int u = __float_as_uint(f);
  u += 0x7fffu + ((u >> 16) & 1u);   // RNE
  return (unsigned short)(u >> 16);
}
static __device__ __forceinline__ float sigf(float x) {
  return 1.f / (1.f + __expf(-x));
}
static __device__ __forceinline__ float tanh_fast(float x) {
  const float e = __expf(-2.f * fabsf(x));
  const float r = (1.f - e) / (1.f + e);
  return copysignf(r, x);
}

// ---------------------------------------------------------------------------
// Kernel A: attn[b,d] = softmax_d( sum_t in[b,t,d]*wx[t] ); out0 = attn*in
// ---------------------------------------------------------------------------
__global__ __launch_bounds__(128) void attn_kernel(
    const float* __restrict__ in, const float* __restrict__ attn_W,
    float* __restrict__ out0, float* __restrict__ attn_ws) {
  const int b = blockIdx.x;
  const int d = threadIdx.x;
  __shared__ float wx[NT];
  __shared__ float red[4];
  wx[d] = attn_W[2 * NH + d];
  __syncthreads();
  const float* ib = in + (size_t)b * (NT * ND);
  float p = 0.f;
#pragma unroll 8
  for (int t = 0; t < NT; ++t) p = fmaf(ib[t * ND + d], wx[t], p);
  float m = p;
#pragma unroll
  for (int off = 32; off >= 1; off >>= 1) m = fmaxf(m, __shfl_xor(m, off));
  const int wv = d >> 6;
  if ((d & 63) == 0) red[wv] = m;
  __syncthreads();
  const float M = fmaxf(red[0], red[1]);
  const float e = expf(p - M);
  float s = e;
#pragma unroll
  for (int off = 32; off >= 1; off >>= 1) s += __shfl_xor(s, off);
  if ((d & 63) == 0) red[2 + wv] = s;
  __syncthreads();
  const float a = e / (red[2] + red[3]);
  attn_ws[b * ND + d] = a;
#pragma unroll 4
  for (int t = 0; t < NT; ++t)
    out0[(size_t)b * (NT * ND) + t * ND + d] = a * ib[t * ND + d];
}

// ---------------------------------------------------------------------------
// Kernel C: persistent fused LSTM recurrence. 256 blocks x 512 thr, 1/CU.
// Block (gid=bid&7, sid=bid>>3): batch rows [gid*64,+64), h-cols [sid*16,+16).
// Wave wid: rw=wid&1 (row half), cg=(wid>>1)&1 (gate pair), kh=wid>>2 (K half).
// W fragments in registers; h tile + wi tile + gate exchange in LDS.
// ---------------------------------------------------------------------------
__global__ __launch_bounds__(512, 2) void rec_kernel(
    const float* __restrict__ in, const float* __restrict__ W_ih,
    const float* __restrict__ W_hh, const float* __restrict__ b_ih,
    const float* __restrict__ b_hh, const float* __restrict__ attn_ws,
    unsigned short* __restrict__ hbuf, unsigned int* __restrict__ flags,
    float* __restrict__ out1) {
  __shared__ __align__(16) unsigned char LDS[LDS_BYTES];
  const int tid = threadIdx.x;
  const int bid = blockIdx.x;
  const int gid = bid & 7;
  const int sid = bid >> 3;
  const int bb0 = gid * 64;
  const int n0 = sid * 16;
  const int lane = tid & 63;
  const int wid = tid >> 6;
  const int rw = wid & 1;
  const int cg = (wid >> 1) & 1;
  const int kh = wid >> 2;
  const int colB = lane & 15;
  const int kg = lane >> 4;

  // --- W fragments -> registers (one-time) ---
  short8 bh[8][2];
  short8 bwi[2][2];
#pragma unroll
  for (int j = 0; j < 2; ++j) {
    const int gate = cg * 2 + j;
    const float* wr_h = W_hh + (size_t)(gate * NH + n0 + colB) * NH;
    const float* wr_i = W_ih + (size_t)(gate * NH + n0 + colB) * ND;
#pragma unroll
    for (int ksl = 0; ksl < 8; ++ksl) {
      const int k0 = (kh * 8 + ksl) * 32 + kg * 8;
      floatx4 f0 = *(const floatx4*)(wr_h + k0);
      floatx4 f1 = *(const floatx4*)(wr_h + k0 + 4);
      short8 s;
#pragma unroll
      for (int i = 0; i < 4; ++i) {
        s[i] = (short)f2bf(f0[i]);
        s[4 + i] = (short)f2bf(f1[i]);
      }
      bh[ksl][j] = s;
    }
#pragma unroll
    for (int ksl = 0; ksl < 2; ++ksl) {
      const int k0 = (kh * 2 + ksl) * 32 + kg * 8;
      floatx4 f0 = *(const floatx4*)(wr_i + k0);
      floatx4 f1 = *(const floatx4*)(wr_i + k0 + 4);
      short8 s;
#pragma unroll
      for (int i = 0; i < 4; ++i) {
        s[i] = (short)f2bf(f0[i]);
        s[4 + i] = (short)f2bf(f1[i]);
      }
      bwi[ksl][j] = s;
    }
  }

  // --- attention weights (t-invariant) ---
  const int rA = tid >> 3;
  const int pA = tid & 7;
  float areg[16];
  {
    const float* ap = attn_ws + (bb0 + rA) * ND + pA * 16;
#pragma unroll
    for (int i = 0; i < 16; ++i) areg[i] = ap[i];
  }
  // --- biases for this thread's output column ---
  const int colC = tid & 15;
  const int jC = n0 + colC;
  const float bi_i = b_ih[jC] + b_hh[jC];
  const float bi_f = b_ih[NH + jC] + b_hh[NH + jC];
  const float bi_g = b_ih[2 * NH + jC] + b_hh[2 * NH + jC];
  const float bi_o = b_ih[3 * NH + jC] + b_hh[3 * NH + jC];
  float creg0 = 0.f, creg1 = 0.f;

  const int rowa0 = rw * 32 + colB;
  const int rowa1 = rowa0 + 16;
  const int swa = (rowa0 & 7) << 4;     // same for rowa1 (+16 preserves &7)
  unsigned int* fslot = flags + (gid * 32 + sid) * 16;
  const unsigned int* fpoll = flags + (gid * 32 + (lane & 31)) * 16;
  const int prow = tid >> 4;

  // --- prologue: stage wi_0 into WT, prefetch x_1 ---
  floatx4 xr4[4];
  {
    const float* xs = in + ((size_t)(bb0 + rA) * NT + 0) * ND + pA * 16;
    floatx4 xv[4];
#pragma unroll
    for (int i = 0; i < 4; ++i) xv[i] = *(const floatx4*)(xs + 4 * i);
    unsigned int w[8];
#pragma unroll
    for (int i = 0; i < 8; ++i) {
      const float v0 = xv[i >> 1][(i & 1) * 2 + 0] * areg[2 * i];
      const float v1 = xv[i >> 1][(i & 1) * 2 + 1] * areg[2 * i + 1];
      w[i] = (unsigned int)f2bf(v0) | ((unsigned int)f2bf(v1) << 16);
    }
    const int base = WT_OFF + rA * 256;
    const int swp = (rA & 7) << 4;
    uintx4 lo = {w[0], w[1], w[2], w[3]};
    uintx4 hi = {w[4], w[5], w[6], w[7]};
    *(uintx4*)&LDS[base + ((pA * 32) ^ swp)] = lo;
    *(uintx4*)&LDS[base + ((pA * 32 + 16) ^ swp)] = hi;
  }
  {
    const float* xs = in + ((size_t)(bb0 + rA) * NT + 1) * ND + pA * 16;
#pragma unroll
    for (int i = 0; i < 4; ++i) xr4[i] = *(const floatx4*)(xs + 4 * i);
  }
  __syncthreads();

  for (int t = 0; t < NT; ++t) {
    // ---- pack wi_{t+1} from xr4 (x_{t+1}) ----
    unsigned int w[8];
#pragma unroll
    for (int i = 0; i < 8; ++i) {
      const float v0 = xr4[i >> 1][(i & 1) * 2 + 0] * areg[2 * i];
      const float v1 = xr4[i >> 1][(i & 1) * 2 + 1] * areg[2 * i + 1];
      w[i] = (unsigned int)f2bf(v0) | ((unsigned int)f2bf(v1) << 16);
    }

    floatx4 acc00 = {0.f, 0.f, 0.f, 0.f};
    floatx4 acc01 = {0.f, 0.f, 0.f, 0.f};
    floatx4 acc10 = {0.f, 0.f, 0.f, 0.f};
    floatx4 acc11 = {0.f, 0.f, 0.f, 0.f};

    if (t > 0) {
      // ---- group sync: wave0 polls per-block flags (parallel, no atomics) --
      if (wid == 0) {
        unsigned int v;
        do {
          asm volatile("global_load_dword %0, %1, off sc0 sc1\n\ts_waitcnt vmcnt(0)"
                       : "=v"(v) : "v"(fpoll) : "memory");
        } while (!__all((int)v >= t));
      }
      __syncthreads();                                    // (a)
      // ---- issue full h-tile MALL loads (128B/thread) ----
      const unsigned short* hsrc = hbuf + (size_t)(t & 1) * (NB * NH);
      uintx4 hq[8];
#pragma unroll
      for (int p = 0; p < 8; ++p) {
        const int idx = p * 512 + tid;
        const int r = idx >> 6, s = idx & 63;
        const unsigned short* src = hsrc + (size_t)(bb0 + r) * NH + s * 8;
        asm volatile("global_load_dwordx4 %0, %1, off sc0 sc1"
                     : "=v"(hq[p]) : "v"(src) : "memory");
      }
      // ---- wi MFMAs overlap the MALL latency ----
#pragma unroll
      for (int ksl = 0; ksl < 2; ++ksl) {
        const int k2 = (kh * 2 + ksl) * 64 + kg * 16;
        short8 a0 = *(const short8*)&LDS[WT_OFF + rowa0 * 256 + (k2 ^ swa)];
        short8 a1 = *(const short8*)&LDS[WT_OFF + rowa1 * 256 + (k2 ^ swa)];
        acc00 = __builtin_amdgcn_mfma_f32_16x16x32_bf16(a0, bwi[ksl][0], acc00, 0, 0, 0);
        acc01 = __builtin_amdgcn_mfma_f32_16x16x32_bf16(a0, bwi[ksl][1], acc01, 0, 0, 0);
        acc10 = __builtin_amdgcn_mfma_f32_16x16x32_bf16(a1, bwi[ksl][0], acc10, 0, 0, 0);
        acc11 = __builtin_amdgcn_mfma_f32_16x16x32_bf16(a1, bwi[ksl][1], acc11, 0, 0, 0);
      }
      asm volatile("s_waitcnt vmcnt(0)" ::: "memory");
      __builtin_amdgcn_sched_barrier(0);
#pragma unroll
      for (int p = 0; p < 8; ++p) {
        const int idx = p * 512 + tid;
        const int r = idx >> 6, s = idx & 63;
        *(uintx4*)&LDS[HH_OFF + r * 1024 + ((s * 16) ^ ((r & 7) << 4))] = hq[p];
      }
      __syncthreads();                                    // (b)
      // ---- stage wi_{t+1} (WT reads all done at (b)) ----
      {
        const int base = WT_OFF + rA * 256;
        const int swp = (rA & 7) << 4;
        uintx4 lo = {w[0], w[1], w[2], w[3]};
        uintx4 hi = {w[4], w[5], w[6], w[7]};
        *(uintx4*)&LDS[base + ((pA * 32) ^ swp)] = lo;
        *(uintx4*)&LDS[base + ((pA * 32 + 16) ^ swp)] = hi;
      }
      // ---- h MFMAs (K-half kh) ----
#pragma unroll
      for (int ksl = 0; ksl < 8; ++ksl) {
        const int k2 = (kh * 8 + ksl) * 64 + kg * 16;
        short8 a0 = *(const short8*)&LDS[HH_OFF + rowa0 * 1024 + (k2 ^ swa)];
        short8 a1 = *(const short8*)&LDS[HH_OFF + rowa1 * 1024 + (k2 ^ swa)];
        acc00 = __builtin_amdgcn_mfma_f32_16x16x32_bf16(a0, bh[ksl][0], acc00, 0, 0, 0);
        acc01 = __builtin_amdgcn_mfma_f32_16x16x32_bf16(a0, bh[ksl][1], acc01, 0, 0, 0);
        acc10 = __builtin_amdgcn_mfma_f32_16x16x32_bf16(a1, bh[ksl][0], acc10, 0, 0, 0);
        acc11 = __builtin_amdgcn_mfma_f32_16x16x32_bf16(a1, bh[ksl][1], acc11, 0, 0, 0);
      }
    } else {
      // t == 0: wi contribution only
#pragma unroll
      for (int ksl = 0; ksl < 2; ++ksl) {
        const int k2 = (kh * 2 + ksl) * 64 + kg * 16;
        short8 a0 = *(const short8*)&LDS[WT_OFF + rowa0 * 256 + (k2 ^ swa)];
        short8 a1 = *(const short8*)&LDS[WT_OFF + rowa1 * 256 + (k2 ^ swa)];
        acc00 = __builtin_amdgcn_mfma_f32_16x16x32_bf16(a0, bwi[ksl][0], acc00, 0, 0, 0);
        acc01 = __builtin_amdgcn_mfma_f32_16x16x32_bf16(a0, bwi[ksl][1], acc01, 0, 0, 0);
        acc10 = __builtin_amdgcn_mfma_f32_16x16x32_bf16(a1, bwi[ksl][0], acc10, 0, 0, 0);
        acc11 = __builtin_amdgcn_mfma_f32_16x16x32_bf16(a1, bwi[ksl][1], acc11, 0, 0, 0);
      }
      __syncthreads();                                    // (a)
      {
        const int base = WT_OFF + rA * 256;
        const int swp = (rA & 7) << 4;
        uintx4 lo = {w[0], w[1], w[2], w[3]};
        uintx4 hi = {w[4], w[5], w[6], w[7]};
        *(uintx4*)&LDS[base + ((pA * 32) ^ swp)] = lo;
        *(uintx4*)&LDS[base + ((pA * 32 + 16) ^ swp)] = hi;
      }
    }
    // ---- write gate partials -> GT[kh][64][66] ----
#pragma unroll
    for (int i = 0; i < 2; ++i)
#pragma unroll
      for (int r = 0; r < 4; ++r) {
        const int row = rw * 32 + i * 16 + kg * 4 + r;
        const int c0 = cg * 32 + colB;
        const floatx4& aL = i ? acc10 : acc00;
        const floatx4& aR = i ? acc11 : acc01;
        *(float*)&LDS[GT_OFF + kh * GT_KH + (row * 66 + c0) * 4] = aL[r];
        *(float*)&LDS[GT_OFF + kh * GT_KH + (row * 66 + c0 + 16) * 4] = aR[r];
      }
    __syncthreads();                                      // (c)
    // ---- LSTM pointwise: 2 cells/thread, sum kh partials + bias ----
    float hn0, hn1;
    {
      const float* g0 = (const float*)&LDS[GT_OFF + (prow * 66) * 4];
      const float* g1 = (const float*)&LDS[GT_OFF + GT_KH + (prow * 66) * 4];
      const float gi = g0[colC] + g1[colC] + bi_i;
      const float gf = g0[16 + colC] + g1[16 + colC] + bi_f;
      const float gg = g0[32 + colC] + g1[32 + colC] + bi_g;
      const float go = g0[48 + colC] + g1[48 + colC] + bi_o;
      const float cn = sigf(gf) * creg0 + sigf(gi) * tanh_fast(gg);
      hn0 = sigf(go) * tanh_fast(cn);
      creg0 = cn;
    }
    {
      const float* g0 = (const float*)&LDS[GT_OFF + ((prow + 32) * 66) * 4];
      const float* g1 = (const float*)&LDS[GT_OFF + GT_KH + ((prow + 32) * 66) * 4];
      const float gi = g0[colC] + g1[colC] + bi_i;
      const float gf = g0[16 + colC] + g1[16 + colC] + bi_f;
      const float gg = g0[32 + colC] + g1[32 + colC] + bi_g;
      const float go = g0[48 + colC] + g1[48 + colC] + bi_o;
      const float cn = sigf(gf) * creg1 + sigf(gi) * tanh_fast(gg);
      hn1 = sigf(go) * tanh_fast(cn);
      creg1 = cn;
    }
    // ---- h hand-off: packed 4B MALL stores ----
    const unsigned int m0 = (unsigned int)f2bf(hn0);
    const unsigned int m1 = (unsigned int)f2bf(hn1);
    const unsigned int o0 = (unsigned int)__shfl_xor((int)m0, 1);
    const unsigned int o1 = (unsigned int)__shfl_xor((int)m1, 1);
    if (!(tid & 1)) {
      unsigned short* hdst = hbuf + (size_t)((t + 1) & 1) * (NB * NH);
      unsigned short* p0 = hdst + (size_t)(bb0 + prow) * NH + jC;
      unsigned short* p1 = hdst + (size_t)(bb0 + 32 + prow) * NH + jC;
      const unsigned int d0 = m0 | (o0 << 16);
      const unsigned int d1 = m1 | (o1 << 16);
      asm volatile("global_store_dword %0, %1, off sc0 sc1" :: "v"(p0), "v"(d0) : "memory");
      asm volatile("global_store_dword %0, %1, off sc0 sc1" :: "v"(p1), "v"(d1) : "memory");
    }
    asm volatile("s_waitcnt vmcnt(0)" ::: "memory");      // h stores ACK'd at MALL
    __syncthreads();                                      // (d)
    if (tid == 0) {
      const unsigned int tv = (unsigned int)(t + 1);
      asm volatile("global_store_dword %0, %1, off sc0 sc1" :: "v"(fslot), "v"(tv) : "memory");
    }
    // ---- off-critical-path: out1 stores + x prefetch ----
    __builtin_nontemporal_store(hn0, &out1[((size_t)(bb0 + prow) * NT + t) * NH + jC]);
    __builtin_nontemporal_store(hn1, &out1[((size_t)(bb0 + 32 + prow) * NT + t) * NH + jC]);
    {
      const int tx = (t + 2 < NT) ? (t + 2) : (NT - 1);
      const float* xs = in + ((size_t)(bb0 + rA) * NT + tx) * ND + pA * 16;
#pragma unroll
      for (int i = 0; i < 4; ++i) xr4[i] = *(const floatx4*)(xs + 4 * i);
    }
  }
}

// ---------------------------------------------------------------------------
extern "C" void kernel_launch(void* const* d_in, const int* in_sizes, int n_in,
                              void* d_out, int out_size, void* d_ws, size_t ws_size,
                              hipStream_t stream) {
  (void)in_sizes; (void)n_in; (void)out_size; (void)ws_size;
  const float* in     = (const float*)d_in[0];
  const float* W_ih   = (const float*)d_in[1];
  const float* W_hh   = (const float*)d_in[2];
  const float* b_ih   = (const float*)d_in[3];
  const float* b_hh   = (const float*)d_in[4];
  const float* attn_W = (const float*)d_in[5];
  // d_in[6] (attn_b) cancels in the softmax -> unused.

  float* out0 = (float*)d_out;                          // (512,128,128)
  float* out1 = out0 + (size_t)NB * NT * ND;            // (512,128,512)

  float* attn_ws = (float*)d_ws;                                     // 256 KB
  unsigned short* hbuf = (unsigned short*)((char*)d_ws + 262144);    // 1 MB
  unsigned int* flags = (unsigned int*)((char*)d_ws + 262144 + 1048576); // 16 KB

  hipMemsetAsync(flags, 0, 16384, stream);
  attn_kernel<<<NB, 128, 0, stream>>>(in, attn_W, out0, attn_ws);
  rec_kernel<<<256, 512, 0, stream>>>(in, W_ih, W_hh, b_ih, b_hh, attn_ws,
                                      hbuf, flags, out1);
}